// Round 12
// baseline (4955.169 us; speedup 1.0000x reference)
//
#include <hip/hip_runtime.h>

#define HDIM  128
#define G3    384
#define RPB   16
#define NTHR  512
#define NSTEP 256
#define NOUT  33
#define BROWS 8192
#define NBLK  (BROWS / RPB)      // 512 blocks -> 2 per CU
#define LOGP_ELEMS 69206016LL    // 8192*256*33
#define PRED_LD 34

typedef _Float16 half8 __attribute__((ext_vector_type(8)));
typedef float    f32x4 __attribute__((ext_vector_type(4)));

// ---------------- LDS byte layout (67776 B -> 2 blocks/CU) ----------------
#define HS0_OFF   0              // h0 splits: [16][256B] swz, split1 at +4096   (8192)
#define HS1_OFF   8192           //                                              (8192)
#define BST_OFF   16384          // ring: 8 waves x 6 slots x 1024 B            (49152)
#define PRED_OFF  65536          // preds [16][34] f32                           (2176)
#define ACTS_OFF  67712          // acts [16] int                                  (64)
#define LDS_BYTES 67776

// ---------------- ws layout ----------------
#define WP_BYTES  294912         // 3 mats x 24 nt x 4 kc x 1024 B (single split)
#define FP_BYTES  24576          // fc: 3 nt x 4 kc x 2 s x 1024 B

__device__ __forceinline__ float sigf(float x) { return 1.0f / (1.0f + __expf(-x)); }
__device__ __forceinline__ float tanh_fast(float x) { return 1.0f - 2.0f / (__expf(2.0f*x) + 1.0f); }

// ---------------- prep: gi0 tables (fp32) ----------------
__global__ void prep_kernel(const float* __restrict__ emb, const float* __restrict__ wih0,
                            const float* __restrict__ bih0, float* __restrict__ T1,
                            float* __restrict__ T0) {
    int a = blockIdx.x;          // 0..31
    int g = threadIdx.x;         // 0..383
    const float* e = emb + a * 127;
    const float* w = wih0 + g * HDIM;
    float s = bih0[g];
    for (int k = 0; k < 127; ++k) s += e[k] * w[k];
    T1[a * G3 + g] = s + w[127];
    if (a == 0) T0[g] = s;
}

// ---------------- prep: pack weights (fp16 single split) + fc (2-split) ----------------
// lane holds B[g = nt*16 + (lane&15)][k = kc*32 + (lane>>4)*8 + e]
__global__ void prep_pack(const float* __restrict__ whh0, const float* __restrict__ wih1,
                          const float* __restrict__ whh1, const float* __restrict__ fcw,
                          half8* __restrict__ WP) {
    int b = blockIdx.x;            // 0..74 : 0-71 weight tiles, 72-74 fc
    int tid  = threadIdx.x;        // 256
    int lane = tid & 63;
    int kc   = tid >> 6;
    bool isfc = (b >= 72);
    if (!isfc) {
        int mat = b / 24, nt = b % 24;
        const float* W = (mat == 0) ? whh0 : (mat == 1) ? wih1 : whh1;
        int g = nt * 16 + (lane & 15);
        int k = kc * 32 + (lane >> 4) * 8;
        half8 v1;
#pragma unroll
        for (int e = 0; e < 8; ++e) v1[e] = (_Float16)W[g * HDIM + k + e];
        WP[(size_t)(((mat * 24 + nt) * 4 + kc)) * 64 + lane] = v1;
    } else {
        int nt = b - 72;
        int g = nt * 16 + (lane & 15);
        int k = kc * 32 + (lane >> 4) * 8;
        half8 v1, v2;
#pragma unroll
        for (int e = 0; e < 8; ++e) {
            float x = (g >= NOUT) ? 0.0f : fcw[g * HDIM + k + e];
            _Float16 s1 = (_Float16)x;
            v1[e] = s1; v2[e] = (_Float16)(x - (float)s1);
        }
        size_t base = (size_t)(WP_BYTES / 1024 + (nt * 4 + kc) * 2) * 64 + lane;
        WP[base]      = v1;
        WP[base + 64] = v2;
    }
}

// ---------------- main decoder: hazard-safe ring, 2 blocks/CU ----------------
__launch_bounds__(NTHR, 4)
__global__ void decoder_kernel(const float* __restrict__ hid,
                               const float* __restrict__ T1, const float* __restrict__ T0,
                               const char* __restrict__ Bpg,
                               const float* __restrict__ bhh0,
                               const float* __restrict__ bih1, const float* __restrict__ bhh1,
                               const float* __restrict__ fcb,
                               float* __restrict__ out) {
    extern __shared__ char smraw[];
    char*  hs0   = smraw + HS0_OFF;
    char*  hs1   = smraw + HS1_OFF;
    char*  bst   = smraw + BST_OFF;
    float* preds = (float*)(smraw + PRED_OFF);
    int*   acts  = (int*)(smraw + ACTS_OFF);

    const int tid  = threadIdx.x;
    const int row0 = blockIdx.x * RPB;
    float* lp = out;
    float* pp = out + LOGP_ELEMS;

    const int lane  = tid & 63;
    const int w     = tid >> 6;      // wave 0..7
    const int col   = lane & 15;
    const int q     = lane >> 4;
    const int akoff = q * 16;        // A-frag byte offset within 64B k-chunk
    const int j     = w * 16 + col;  // gate/hidden column owned by this lane
    char* const mybuf = bst + (size_t)w * 6144;   // 6 slots x 1024 B

    // hoisted per-lane biases
    const float bG0 = bhh0[j],       bG1 = bhh0[128 + j], bG2 = bhh0[256 + j];
    const float bH0 = bhh1[j],       bH1 = bhh1[128 + j], bH2 = bhh1[256 + j];
    const float bI0 = bih1[j],       bI1 = bih1[128 + j], bI2 = bih1[256 + j];

    // fc weights -> 16 VGPR (2-split); waves 0-2 active, tile nt = w
    const int fnt = w % 3;
    const int fo  = fnt * 16 + col;
    const float fbias = (fo < NOUT) ? fcb[fo] : 0.0f;
    half8 fcr[4][2];
#pragma unroll
    for (int kc = 0; kc < 4; ++kc)
#pragma unroll
        for (int s = 0; s < 2; ++s)
            fcr[kc][s] = *(const half8*)(Bpg + WP_BYTES +
                (size_t)(((fnt * 4 + kc) * 2 + s) * 1024) + lane * 16);

    // ---- init h0/h1 -> VGPRs + fp16 2-splits to LDS ----
    float h0v[4], h1v[4];
#pragma unroll
    for (int i = 0; i < 4; ++i) {
        int row = q * 4 + i;
        float v0 = hid[(size_t)(row0 + row) * HDIM + j];
        float v1 = hid[(size_t)BROWS * HDIM + (size_t)(row0 + row) * HDIM + j];
        h0v[i] = v0; h1v[i] = v1;
        int off = (row * 256 + j * 2) ^ ((row & 7) << 4);
        _Float16 s1 = (_Float16)v0, s2 = (_Float16)(v0 - (float)s1);
        *(_Float16*)(hs0 + off) = s1;
        *(_Float16*)(hs0 + 4096 + off) = s2;
        s1 = (_Float16)v1; s2 = (_Float16)(v1 - (float)s1);
        *(_Float16*)(hs1 + off) = s1;
        *(_Float16*)(hs1 + 4096 + off) = s2;
    }
    asm volatile("s_waitcnt lgkmcnt(0)" ::: "memory");
    __builtin_amdgcn_s_barrier();

#define LGKM0() asm volatile("s_waitcnt lgkmcnt(0)" ::: "memory")
#define VMW()   asm volatile("s_waitcnt vmcnt(4)" ::: "memory")
#define BAR()   __builtin_amdgcn_s_barrier()
#define MFMA(a, b, c) __builtin_amdgcn_mfma_f32_16x16x32_f16((a), (b), (c), 0, 0, 0)

    // per-step chunk c in [0,36): c<12 -> mat0 (gh0), c<24 -> mat2 (gh1), else mat1 (gi1)
    // within a phase: p = c%12, kc = p/3, ty = p%3; nt = ty*8 + w; tile = 1024 B.
    // ring slot = c % 6 (36 % 6 == 0 -> step-invariant).
    // stage-ahead 4 = depth-2: STAGE(C+4) writes slot (C-2)%6 -> 2 chunks of slack
    // after that slot's last ds_read (overwrite-hazard safe, the R11-proven margin).
    // vmcnt(4) exact by in-order retirement; interloper loads only make it stricter.
#define STAGE(C_) do {                                                            \
        int cm_  = (C_) % 36;                                                     \
        int mat_ = (cm_ < 12) ? 0 : ((cm_ < 24) ? 2 : 1);                         \
        int p_   = cm_ % 12;                                                      \
        int kc_  = p_ / 3, ty_ = p_ % 3;                                          \
        char* dst_ = mybuf + (size_t)((C_) % 6) * 1024;                           \
        const char* src_ = Bpg + (size_t)(((mat_ * 24 + (ty_ * 8 + w)) * 4 + kc_) * 1024) + lane * 16; \
        __builtin_amdgcn_global_load_lds((const unsigned int*)src_,               \
                                         (unsigned int*)dst_, 16, 0, 0);          \
    } while (0)

#define CHUNK(C_, A1_, A2_, ACC_) do {                                            \
        STAGE((C_) + 4);                                                          \
        VMW();                                                                    \
        half8 b_ = *(const half8*)(mybuf + (size_t)((C_) % 6) * 1024 + lane * 16);\
        ACC_ = MFMA(A1_, b_, ACC_);                                               \
        ACC_ = MFMA(A2_, b_, ACC_);                                               \
    } while (0)

    // one kc-group: hoist 2 A-frag reads, run the 3 ty-chunks
#define KC3(BASE_, KC_, HS_, ACC_) do {                                           \
        int offA_ = (col * 256 + (KC_) * 64 + akoff) ^ ((col & 7) << 4);          \
        half8 a1_ = *(const half8*)((HS_) + offA_);                               \
        half8 a2_ = *(const half8*)((HS_) + 4096 + offA_);                        \
        CHUNK((BASE_) + (KC_) * 3 + 0, a1_, a2_, ACC_[0]);                        \
        CHUNK((BASE_) + (KC_) * 3 + 1, a1_, a2_, ACC_[1]);                        \
        CHUNK((BASE_) + (KC_) * 3 + 2, a1_, a2_, ACC_[2]);                        \
    } while (0)

    // prologue: stage chunks 0..3
    STAGE(0); STAGE(1); STAGE(2); STAGE(3);

#pragma unroll 1
    for (int t = 0; t < NSTEP; ++t) {
        // ---- T-table gather (acts from prev step; latency hides under phase A) ----
        float gi[3][4];
        if (t == 0) {
            float g0v = T0[j], g1v = T0[128 + j], g2v = T0[256 + j];
#pragma unroll
            for (int i = 0; i < 4; ++i) {
                gi[0][i] = g0v; gi[1][i] = g1v; gi[2][i] = g2v;
            }
        } else {
#pragma unroll
            for (int i = 0; i < 4; ++i) {
                const float* tab = T1 + acts[q * 4 + i] * G3;
                gi[0][i] = tab[j];
                gi[1][i] = tab[128 + j];
                gi[2][i] = tab[256 + j];
            }
        }

        // ---- phase A: gh0 (c0-11, A=hs0 old) and gh1 (c12-23, A=hs1 old) ----
        f32x4 g0[3], ah[3];
        {
            f32x4 v0 = {bG0, bG0, bG0, bG0}, v1 = {bG1, bG1, bG1, bG1}, v2 = {bG2, bG2, bG2, bG2};
            g0[0] = v0; g0[1] = v1; g0[2] = v2;
            f32x4 u0 = {bH0, bH0, bH0, bH0}, u1 = {bH1, bH1, bH1, bH1}, u2 = {bH2, bH2, bH2, bH2};
            ah[0] = u0; ah[1] = u1; ah[2] = u2;
        }
        KC3(0, 0, hs0, g0); KC3(0, 1, hs0, g0); KC3(0, 2, hs0, g0); KC3(0, 3, hs0, g0);
        KC3(12, 0, hs1, ah); KC3(12, 1, hs1, ah); KC3(12, 2, hs1, ah); KC3(12, 3, hs1, ah);
        LGKM0(); BAR();   // BAR1: all hs0/hs1 reads done before rewrites

        // ---- gates0: h0_new -> VGPR + hs0 splits ----
#pragma unroll
        for (int i = 0; i < 4; ++i) {
            float rg = sigf(gi[0][i] + g0[0][i]);
            float zg = sigf(gi[1][i] + g0[1][i]);
            float ng = tanh_fast(gi[2][i] + rg * g0[2][i]);
            float hnew = (1.0f - zg) * ng + zg * h0v[i];
            h0v[i] = hnew;
            int row = q * 4 + i;
            int off = (row * 256 + j * 2) ^ ((row & 7) << 4);
            _Float16 s1 = (_Float16)hnew, s2 = (_Float16)(hnew - (float)s1);
            *(_Float16*)(hs0 + off) = s1;
            *(_Float16*)(hs0 + 4096 + off) = s2;
        }
        LGKM0(); BAR();   // BAR2: hs0_new visible

        // ---- phase B: gi1 (c24-35, mat1, A=hs0_new) ----
        f32x4 ai[3];
        {
            f32x4 v0 = {bI0, bI0, bI0, bI0}, v1 = {bI1, bI1, bI1, bI1}, v2 = {bI2, bI2, bI2, bI2};
            ai[0] = v0; ai[1] = v1; ai[2] = v2;
        }
        KC3(24, 0, hs0, ai); KC3(24, 1, hs0, ai); KC3(24, 2, hs0, ai); KC3(24, 3, hs0, ai);

        // ---- gates1: h1_new -> VGPR + hs1 splits (hs1 reads fenced by BAR1) ----
#pragma unroll
        for (int i = 0; i < 4; ++i) {
            float rg = sigf(ai[0][i] + ah[0][i]);
            float zg = sigf(ai[1][i] + ah[1][i]);
            float ng = tanh_fast(ai[2][i] + rg * ah[2][i]);
            float hnew = (1.0f - zg) * ng + zg * h1v[i];
            h1v[i] = hnew;
            int row = q * 4 + i;
            int off = (row * 256 + j * 2) ^ ((row & 7) << 4);
            _Float16 s1 = (_Float16)hnew, s2 = (_Float16)(hnew - (float)s1);
            *(_Float16*)(hs1 + off) = s1;
            *(_Float16*)(hs1 + 4096 + off) = s2;
        }
        LGKM0(); BAR();   // BAR3: hs1_new visible

        // ---- fc: preds = h1_new.fc_w^T + fc_b (waves 0-2, B in VGPRs) ----
        if (w < 3) {
            f32x4 acc = {fbias, fbias, fbias, fbias};
#pragma unroll
            for (int kc = 0; kc < 4; ++kc) {
                int off = (col * 256 + kc * 64 + akoff) ^ ((col & 7) << 4);
                half8 a1 = *(const half8*)(hs1 + off);
                half8 a2 = *(const half8*)(hs1 + 4096 + off);
                acc = MFMA(a1, fcr[kc][0], acc);
                acc = MFMA(a2, fcr[kc][0], acc);
                acc = MFMA(a1, fcr[kc][1], acc);
            }
            if (fo < NOUT) {
#pragma unroll
                for (int i = 0; i < 4; ++i)
                    preds[(q * 4 + i) * PRED_LD + fo] = acc[i];
            }
        }
        LGKM0(); BAR();   // BAR4: preds visible

        // ---- softmax/log_softmax + argmax (first-index) + store ----
        if (tid < 256) {
            int r = tid >> 4; int l16 = tid & 15; int c0 = l16 * 2;
            float v0 = preds[r * PRED_LD + c0];
            float v1 = preds[r * PRED_LD + c0 + 1];
            float bv; int bi;
            if (v0 >= v1) { bv = v0; bi = c0; } else { bv = v1; bi = c0 + 1; }
#pragma unroll
            for (int d = 1; d < 16; d <<= 1) {
                float ov = __shfl_xor(bv, d);
                int   oi = __shfl_xor(bi, d);
                if (ov > bv || (ov == bv && oi < bi)) { bv = ov; bi = oi; }
            }
            float e0 = __expf(v0 - bv), e1 = __expf(v1 - bv);
            float s = e0 + e1;
#pragma unroll
            for (int d = 1; d < 16; d <<= 1) s += __shfl_xor(s, d);
            float ls = __logf(s);
            float inv = 1.0f / s;
            size_t base = ((size_t)(row0 + r) * NSTEP + t) * NOUT;
            lp[base + c0]     = v0 - bv - ls;
            lp[base + c0 + 1] = v1 - bv - ls;
            pp[base + c0]     = e0 * inv;
            pp[base + c0 + 1] = e1 * inv;
            if (l16 == 0) {
                acts[r] = bi;
                lp[base + 32] = preds[r * PRED_LD + 32];  // raw duration logit stash
            }
        }
        LGKM0(); BAR();   // BAR5: acts visible for next step
    }
#undef STAGE
#undef CHUNK
#undef KC3
#undef LGKM0
#undef VMW
#undef BAR
#undef MFMA
}

// ---------------- duration softmax over time ----------------
__global__ void dur_kernel(float* __restrict__ out) {
    int wid  = threadIdx.x >> 6;
    int lane = threadIdx.x & 63;
    int row  = blockIdx.x * 4 + wid;
    float* lp = out;
    float* pp = out + LOGP_ELEMS;
    size_t base = (size_t)row * NSTEP * NOUT + 32;

    float v[4]; float m = -1e30f;
#pragma unroll
    for (int i = 0; i < 4; ++i) {
        v[i] = lp[base + (size_t)(lane * 4 + i) * NOUT];
        m = fmaxf(m, v[i]);
    }
#pragma unroll
    for (int d = 1; d < 64; d <<= 1) m = fmaxf(m, __shfl_xor(m, d));
    float e[4]; float s = 0.0f;
#pragma unroll
    for (int i = 0; i < 4; ++i) { e[i] = __expf(v[i] - m); s += e[i]; }
#pragma unroll
    for (int d = 1; d < 64; d <<= 1) s += __shfl_xor(s, d);
    float inv = 1.0f / s;
#pragma unroll
    for (int i = 0; i < 4; ++i) {
        size_t idx = base + (size_t)(lane * 4 + i) * NOUT;
        float dv = e[i] * inv;
        lp[idx] = dv;
        pp[idx] = dv;
    }
}

extern "C" void kernel_launch(void* const* d_in, const int* in_sizes, int n_in,
                              void* d_out, int out_size, void* d_ws, size_t ws_size,
                              hipStream_t stream) {
    const float* hid  = (const float*)d_in[1];
    const float* emb  = (const float*)d_in[2];
    const float* wih0 = (const float*)d_in[3];
    const float* whh0 = (const float*)d_in[4];
    const float* bih0 = (const float*)d_in[5];
    const float* bhh0 = (const float*)d_in[6];
    const float* wih1 = (const float*)d_in[7];
    const float* whh1 = (const float*)d_in[8];
    const float* bih1 = (const float*)d_in[9];
    const float* bhh1 = (const float*)d_in[10];
    const float* fcw  = (const float*)d_in[11];
    const float* fcb  = (const float*)d_in[12];

    char*  ws = (char*)d_ws;
    half8* WP = (half8*)ws;                               // WP_BYTES + FP_BYTES
    float* T1 = (float*)(ws + WP_BYTES + FP_BYTES);       // 32*384 f32
    float* T0 = T1 + 32 * G3;                             // 384 f32

    prep_kernel<<<32, 384, 0, stream>>>(emb, wih0, bih0, T1, T0);
    prep_pack<<<75, 256, 0, stream>>>(whh0, wih1, whh1, fcw, WP);

    hipFuncSetAttribute((const void*)decoder_kernel,
                        hipFuncAttributeMaxDynamicSharedMemorySize, LDS_BYTES);
    decoder_kernel<<<NBLK, NTHR, LDS_BYTES, stream>>>(
        hid, T1, T0, ws, bhh0, bih1, bhh1, fcb, (float*)d_out);

    dur_kernel<<<BROWS / 4, 256, 0, stream>>>((float*)d_out);
}

// Round 13
// 3039.812 us; speedup vs baseline: 1.6301x; 1.6301x over previous
//
#include <hip/hip_runtime.h>

#define HDIM  128
#define G3    384
#define RPB   32
#define NTHR  512
#define NSTEP 256
#define NOUT  33
#define BROWS 8192
#define NBLK  (BROWS / RPB)      // 256 blocks -> 1 per CU
#define LOGP_ELEMS 69206016LL    // 8192*256*33
#define PRED_LD 34

typedef _Float16 half8 __attribute__((ext_vector_type(8)));
typedef float    f32x4 __attribute__((ext_vector_type(4)));

// ---------------- LDS byte layout (135552 B, 1 block/CU) ----------------
#define HS0_OFF   0              // h0 splits: [32][256B] swz, split1 at +8192  (16384)
#define HS1_OFF   16384          //                                             (16384)
#define BST_OFF   32768          // ring: 8 waves x 12 slots x 1024 B          (98304)
#define PRED_OFF  131072         // preds [32][34] f32                          (4352)
#define ACTS_OFF  135424         // acts [32] int                                (128)
#define LDS_BYTES 135552

// ---------------- ws layout ----------------
#define WP_BYTES  294912         // 3 mats x 24 nt x 4 kc x 1024 B (single split)
#define FP_BYTES  24576          // fc: 3 nt x 4 kc x 2 s x 1024 B

__device__ __forceinline__ float sigf(float x) { return 1.0f / (1.0f + __expf(-x)); }
__device__ __forceinline__ float tanh_fast(float x) { return 1.0f - 2.0f / (__expf(2.0f*x) + 1.0f); }

// ---------------- prep: gi0 tables (fp32) ----------------
__global__ void prep_kernel(const float* __restrict__ emb, const float* __restrict__ wih0,
                            const float* __restrict__ bih0, float* __restrict__ T1,
                            float* __restrict__ T0) {
    int a = blockIdx.x;          // 0..31
    int g = threadIdx.x;         // 0..383
    const float* e = emb + a * 127;
    const float* w = wih0 + g * HDIM;
    float s = bih0[g];
    for (int k = 0; k < 127; ++k) s += e[k] * w[k];
    T1[a * G3 + g] = s + w[127];
    if (a == 0) T0[g] = s;
}

// ---------------- prep: pack weights (fp16 single split) + fc (2-split) ----------------
// lane holds B[g = nt*16 + (lane&15)][k = kc*32 + (lane>>4)*8 + e]
__global__ void prep_pack(const float* __restrict__ whh0, const float* __restrict__ wih1,
                          const float* __restrict__ whh1, const float* __restrict__ fcw,
                          half8* __restrict__ WP) {
    int b = blockIdx.x;            // 0..74 : 0-71 weight tiles, 72-74 fc
    int tid  = threadIdx.x;        // 256
    int lane = tid & 63;
    int kc   = tid >> 6;
    bool isfc = (b >= 72);
    if (!isfc) {
        int mat = b / 24, nt = b % 24;
        const float* W = (mat == 0) ? whh0 : (mat == 1) ? wih1 : whh1;
        int g = nt * 16 + (lane & 15);
        int k = kc * 32 + (lane >> 4) * 8;
        half8 v1;
#pragma unroll
        for (int e = 0; e < 8; ++e) v1[e] = (_Float16)W[g * HDIM + k + e];
        WP[(size_t)(((mat * 24 + nt) * 4 + kc)) * 64 + lane] = v1;
    } else {
        int nt = b - 72;
        int g = nt * 16 + (lane & 15);
        int k = kc * 32 + (lane >> 4) * 8;
        half8 v1, v2;
#pragma unroll
        for (int e = 0; e < 8; ++e) {
            float x = (g >= NOUT) ? 0.0f : fcw[g * HDIM + k + e];
            _Float16 s1 = (_Float16)x;
            v1[e] = s1; v2[e] = (_Float16)(x - (float)s1);
        }
        size_t base = (size_t)(WP_BYTES / 1024 + (nt * 4 + kc) * 2) * 64 + lane;
        WP[base]      = v1;
        WP[base + 64] = v2;
    }
}

// ---------------- main decoder: group-of-3 staged ring (R11 arithmetic) ----------------
__launch_bounds__(NTHR, 2)
__global__ void decoder_kernel(const float* __restrict__ hid,
                               const float* __restrict__ T1, const float* __restrict__ T0,
                               const char* __restrict__ Bpg,
                               const float* __restrict__ bhh0,
                               const float* __restrict__ bih1, const float* __restrict__ bhh1,
                               const float* __restrict__ fcb,
                               float* __restrict__ out) {
    extern __shared__ char smraw[];
    char*  hs0   = smraw + HS0_OFF;
    char*  hs1   = smraw + HS1_OFF;
    char*  bst   = smraw + BST_OFF;
    float* preds = (float*)(smraw + PRED_OFF);
    int*   acts  = (int*)(smraw + ACTS_OFF);

    const int tid  = threadIdx.x;
    const int row0 = blockIdx.x * RPB;
    float* lp = out;
    float* pp = out + LOGP_ELEMS;

    const int lane  = tid & 63;
    const int w     = tid >> 6;      // wave 0..7
    const int col   = lane & 15;
    const int q     = lane >> 4;
    const int akoff = q * 16;        // A-frag byte offset within 64B k-chunk
    const int j     = w * 16 + col;  // gate/hidden column owned by this lane
    char* const mybuf = bst + (size_t)w * 12288;   // 12 slots x 1024 B

    // hoisted per-lane biases
    const float bG0 = bhh0[j],       bG1 = bhh0[128 + j], bG2 = bhh0[256 + j];
    const float bH0 = bhh1[j],       bH1 = bhh1[128 + j], bH2 = bhh1[256 + j];
    const float bI0 = bih1[j],       bI1 = bih1[128 + j], bI2 = bih1[256 + j];

    // fc weights -> 16 VGPR (2-split); wave (fMt = w/3, fnt = w%3), waves 0-5 active
    const int fnt = w % 3, fMt = (w / 3) & 1;
    const int fo  = fnt * 16 + col;
    const float fbias = (fo < NOUT) ? fcb[fo] : 0.0f;
    half8 fcr[4][2];
#pragma unroll
    for (int kc = 0; kc < 4; ++kc)
#pragma unroll
        for (int s = 0; s < 2; ++s)
            fcr[kc][s] = *(const half8*)(Bpg + WP_BYTES +
                (size_t)(((fnt * 4 + kc) * 2 + s) * 1024) + lane * 16);

    // ---- init h0/h1 -> VGPRs + fp16 2-splits to LDS ----
    float h0v[2][4], h1v[2][4];
#pragma unroll
    for (int Mt = 0; Mt < 2; ++Mt)
#pragma unroll
        for (int i = 0; i < 4; ++i) {
            int row = Mt * 16 + q * 4 + i;
            float v0 = hid[(size_t)(row0 + row) * HDIM + j];
            float v1 = hid[(size_t)BROWS * HDIM + (size_t)(row0 + row) * HDIM + j];
            h0v[Mt][i] = v0; h1v[Mt][i] = v1;
            int off = (row * 256 + j * 2) ^ ((row & 7) << 4);
            _Float16 s1 = (_Float16)v0, s2 = (_Float16)(v0 - (float)s1);
            *(_Float16*)(hs0 + off) = s1;
            *(_Float16*)(hs0 + 8192 + off) = s2;
            s1 = (_Float16)v1; s2 = (_Float16)(v1 - (float)s1);
            *(_Float16*)(hs1 + off) = s1;
            *(_Float16*)(hs1 + 8192 + off) = s2;
        }
    asm volatile("s_waitcnt lgkmcnt(0)" ::: "memory");
    __builtin_amdgcn_s_barrier();

#define LGKM0() asm volatile("s_waitcnt lgkmcnt(0)" ::: "memory")
#define VMW()   asm volatile("s_waitcnt vmcnt(9)" ::: "memory")
#define BAR()   __builtin_amdgcn_s_barrier()
#define MFMA(a, b, c) __builtin_amdgcn_mfma_f32_16x16x32_f16((a), (b), (c), 0, 0, 0)

    // Groups: per step, 12 groups of 3 chunks (one kc x 3 ty tiles).
    // Group g (0..11): g<4 -> mat0 (gh0), g<8 -> mat2 (gh1), else mat1 (gi1); kc = g%4.
    // Chunk C = 3*G + ty; ring slot = C % 12; group slot-base = 3*(G%4).
    // Stage-ahead 3 groups (9 chunks): STAGE3(G+3) writes slots of group (G-1)%4 ->
    // 3 chunks of post-read slack (>= the R11-proven hazard margin).
    // vmcnt(9): 9 chunks staged after group G's last chunk -> group G retired
    // regardless of interloper loads (youngest-9 argument).
#define STAGE3(G_) do {                                                           \
        int gm_  = (G_) % 12;                                                     \
        int mat_ = (gm_ < 4) ? 0 : ((gm_ < 8) ? 2 : 1);                           \
        int kc_  = gm_ & 3;                                                       \
        char* db_ = mybuf + (size_t)(3 * ((G_) & 3)) * 1024;                      \
        _Pragma("unroll")                                                         \
        for (int ty_ = 0; ty_ < 3; ++ty_) {                                       \
            const char* src_ = Bpg + (size_t)(((mat_ * 24 + (ty_ * 8 + w)) * 4 + kc_) * 1024) + lane * 16; \
            __builtin_amdgcn_global_load_lds((const unsigned int*)src_,           \
                                             (unsigned int*)(db_ + ty_ * 1024), 16, 0, 0); \
        }                                                                         \
    } while (0)

    // one group: stage ahead, wait, 5 pipelined ds_reads, 12 MFMAs
    // (per-accumulator MFMA order identical to R11: ty-major, Mt, a1 then a2, kc asc)
#define GROUP(G_, HS_, ACC_) do {                                                 \
        STAGE3((G_) + 3);                                                         \
        VMW();                                                                    \
        int kc_ = (G_) & 3;                                                       \
        half8 a1_[2], a2_[2];                                                     \
        _Pragma("unroll")                                                         \
        for (int Mt_ = 0; Mt_ < 2; ++Mt_) {                                       \
            int row_ = Mt_ * 16 + col;                                            \
            int off_ = (row_ * 256 + kc_ * 64 + akoff) ^ ((row_ & 7) << 4);       \
            a1_[Mt_] = *(const half8*)((HS_) + off_);                             \
            a2_[Mt_] = *(const half8*)((HS_) + 8192 + off_);                      \
        }                                                                         \
        char* db_ = mybuf + (size_t)(3 * ((G_) & 3)) * 1024;                      \
        half8 b0_ = *(const half8*)(db_ + lane * 16);                             \
        half8 b1_ = *(const half8*)(db_ + 1024 + lane * 16);                      \
        half8 b2_ = *(const half8*)(db_ + 2048 + lane * 16);                      \
        _Pragma("unroll")                                                         \
        for (int Mt_ = 0; Mt_ < 2; ++Mt_) {                                       \
            ACC_[0][Mt_] = MFMA(a1_[Mt_], b0_, ACC_[0][Mt_]);                     \
            ACC_[0][Mt_] = MFMA(a2_[Mt_], b0_, ACC_[0][Mt_]);                     \
        }                                                                         \
        _Pragma("unroll")                                                         \
        for (int Mt_ = 0; Mt_ < 2; ++Mt_) {                                       \
            ACC_[1][Mt_] = MFMA(a1_[Mt_], b1_, ACC_[1][Mt_]);                     \
            ACC_[1][Mt_] = MFMA(a2_[Mt_], b1_, ACC_[1][Mt_]);                     \
        }                                                                         \
        _Pragma("unroll")                                                         \
        for (int Mt_ = 0; Mt_ < 2; ++Mt_) {                                       \
            ACC_[2][Mt_] = MFMA(a1_[Mt_], b2_, ACC_[2][Mt_]);                     \
            ACC_[2][Mt_] = MFMA(a2_[Mt_], b2_, ACC_[2][Mt_]);                     \
        }                                                                         \
    } while (0)

    // prologue: stage groups 0..2 (9 chunks)
    STAGE3(0); STAGE3(1); STAGE3(2);

#pragma unroll 1
    for (int t = 0; t < NSTEP; ++t) {
        // ---- T-table gather (acts from prev step; latency hides under phase A) ----
        float gi[3][2][4];
        if (t == 0) {
            float g0v = T0[j], g1v = T0[128 + j], g2v = T0[256 + j];
#pragma unroll
            for (int Mt = 0; Mt < 2; ++Mt)
#pragma unroll
                for (int i = 0; i < 4; ++i) {
                    gi[0][Mt][i] = g0v; gi[1][Mt][i] = g1v; gi[2][Mt][i] = g2v;
                }
        } else {
#pragma unroll
            for (int Mt = 0; Mt < 2; ++Mt)
#pragma unroll
                for (int i = 0; i < 4; ++i) {
                    const float* tab = T1 + acts[Mt * 16 + q * 4 + i] * G3;
                    gi[0][Mt][i] = tab[j];
                    gi[1][Mt][i] = tab[128 + j];
                    gi[2][Mt][i] = tab[256 + j];
                }
        }

        // ---- phase A: gh0 (groups 0-3, A=hs0 old) and gh1 (groups 4-7, A=hs1 old) ----
        f32x4 g0[3][2], ah[3][2];
        {
            f32x4 v0 = {bG0, bG0, bG0, bG0}, v1 = {bG1, bG1, bG1, bG1}, v2 = {bG2, bG2, bG2, bG2};
            g0[0][0] = v0; g0[0][1] = v0; g0[1][0] = v1; g0[1][1] = v1; g0[2][0] = v2; g0[2][1] = v2;
            f32x4 u0 = {bH0, bH0, bH0, bH0}, u1 = {bH1, bH1, bH1, bH1}, u2 = {bH2, bH2, bH2, bH2};
            ah[0][0] = u0; ah[0][1] = u0; ah[1][0] = u1; ah[1][1] = u1; ah[2][0] = u2; ah[2][1] = u2;
        }
        GROUP(0, hs0, g0); GROUP(1, hs0, g0); GROUP(2, hs0, g0); GROUP(3, hs0, g0);
        GROUP(4, hs1, ah); GROUP(5, hs1, ah); GROUP(6, hs1, ah); GROUP(7, hs1, ah);
        LGKM0(); BAR();   // BAR1: all hs0/hs1 reads done before rewrites

        // ---- gates0: h0_new -> VGPR + hs0 splits ----
#pragma unroll
        for (int Mt = 0; Mt < 2; ++Mt)
#pragma unroll
            for (int i = 0; i < 4; ++i) {
                float rg = sigf(gi[0][Mt][i] + g0[0][Mt][i]);
                float zg = sigf(gi[1][Mt][i] + g0[1][Mt][i]);
                float ng = tanh_fast(gi[2][Mt][i] + rg * g0[2][Mt][i]);
                float hnew = (1.0f - zg) * ng + zg * h0v[Mt][i];
                h0v[Mt][i] = hnew;
                int row = Mt * 16 + q * 4 + i;
                int off = (row * 256 + j * 2) ^ ((row & 7) << 4);
                _Float16 s1 = (_Float16)hnew, s2 = (_Float16)(hnew - (float)s1);
                *(_Float16*)(hs0 + off) = s1;
                *(_Float16*)(hs0 + 8192 + off) = s2;
            }
        LGKM0(); BAR();   // BAR2: hs0_new visible

        // ---- phase B: gi1 (groups 8-11, mat1, A=hs0_new) ----
        f32x4 ai[3][2];
        {
            f32x4 v0 = {bI0, bI0, bI0, bI0}, v1 = {bI1, bI1, bI1, bI1}, v2 = {bI2, bI2, bI2, bI2};
            ai[0][0] = v0; ai[0][1] = v0; ai[1][0] = v1; ai[1][1] = v1; ai[2][0] = v2; ai[2][1] = v2;
        }
        GROUP(8, hs0, ai); GROUP(9, hs0, ai); GROUP(10, hs0, ai); GROUP(11, hs0, ai);

        // ---- gates1: h1_new -> VGPR + hs1 splits (hs1 reads fenced by BAR1) ----
#pragma unroll
        for (int Mt = 0; Mt < 2; ++Mt)
#pragma unroll
            for (int i = 0; i < 4; ++i) {
                float rg = sigf(ai[0][Mt][i] + ah[0][Mt][i]);
                float zg = sigf(ai[1][Mt][i] + ah[1][Mt][i]);
                float ng = tanh_fast(ai[2][Mt][i] + rg * ah[2][Mt][i]);
                float hnew = (1.0f - zg) * ng + zg * h1v[Mt][i];
                h1v[Mt][i] = hnew;
                int row = Mt * 16 + q * 4 + i;
                int off = (row * 256 + j * 2) ^ ((row & 7) << 4);
                _Float16 s1 = (_Float16)hnew, s2 = (_Float16)(hnew - (float)s1);
                *(_Float16*)(hs1 + off) = s1;
                *(_Float16*)(hs1 + 8192 + off) = s2;
            }
        LGKM0(); BAR();   // BAR3: hs1_new visible

        // ---- fc: preds = h1_new.fc_w^T + fc_b (waves 0-5, B in VGPRs) ----
        if (w < 6) {
            f32x4 acc = {fbias, fbias, fbias, fbias};
#pragma unroll
            for (int kc = 0; kc < 4; ++kc) {
                int row = fMt * 16 + col;
                int off = (row * 256 + kc * 64 + akoff) ^ ((row & 7) << 4);
                half8 a1 = *(const half8*)(hs1 + off);
                half8 a2 = *(const half8*)(hs1 + 8192 + off);
                acc = MFMA(a1, fcr[kc][0], acc);
                acc = MFMA(a2, fcr[kc][0], acc);
                acc = MFMA(a1, fcr[kc][1], acc);
            }
            if (fo < NOUT) {
#pragma unroll
                for (int i = 0; i < 4; ++i)
                    preds[(fMt * 16 + q * 4 + i) * PRED_LD + fo] = acc[i];
            }
        }
        LGKM0(); BAR();   // BAR4: preds visible

        // ---- softmax/log_softmax + argmax (first-index) + store ----
        {
            int r = tid >> 4; int l16 = tid & 15; int c0 = l16 * 2;
            float v0 = preds[r * PRED_LD + c0];
            float v1 = preds[r * PRED_LD + c0 + 1];
            float bv; int bi;
            if (v0 >= v1) { bv = v0; bi = c0; } else { bv = v1; bi = c0 + 1; }
#pragma unroll
            for (int d = 1; d < 16; d <<= 1) {
                float ov = __shfl_xor(bv, d);
                int   oi = __shfl_xor(bi, d);
                if (ov > bv || (ov == bv && oi < bi)) { bv = ov; bi = oi; }
            }
            float e0 = __expf(v0 - bv), e1 = __expf(v1 - bv);
            float s = e0 + e1;
#pragma unroll
            for (int d = 1; d < 16; d <<= 1) s += __shfl_xor(s, d);
            float ls = __logf(s);
            float inv = 1.0f / s;
            size_t base = ((size_t)(row0 + r) * NSTEP + t) * NOUT;
            lp[base + c0]     = v0 - bv - ls;
            lp[base + c0 + 1] = v1 - bv - ls;
            pp[base + c0]     = e0 * inv;
            pp[base + c0 + 1] = e1 * inv;
            if (l16 == 0) {
                acts[r] = bi;
                lp[base + 32] = preds[r * PRED_LD + 32];  // raw duration logit stash
            }
        }
        LGKM0(); BAR();   // BAR5: acts visible for next step
    }
#undef STAGE3
#undef GROUP
#undef LGKM0
#undef VMW
#undef BAR
#undef MFMA
}

// ---------------- duration softmax over time ----------------
__global__ void dur_kernel(float* __restrict__ out) {
    int wid  = threadIdx.x >> 6;
    int lane = threadIdx.x & 63;
    int row  = blockIdx.x * 4 + wid;
    float* lp = out;
    float* pp = out + LOGP_ELEMS;
    size_t base = (size_t)row * NSTEP * NOUT + 32;

    float v[4]; float m = -1e30f;
#pragma unroll
    for (int i = 0; i < 4; ++i) {
        v[i] = lp[base + (size_t)(lane * 4 + i) * NOUT];
        m = fmaxf(m, v[i]);
    }
#pragma unroll
    for (int d = 1; d < 64; d <<= 1) m = fmaxf(m, __shfl_xor(m, d));
    float e[4]; float s = 0.0f;
#pragma unroll
    for (int i = 0; i < 4; ++i) { e[i] = __expf(v[i] - m); s += e[i]; }
#pragma unroll
    for (int d = 1; d < 64; d <<= 1) s += __shfl_xor(s, d);
    float inv = 1.0f / s;
#pragma unroll
    for (int i = 0; i < 4; ++i) {
        size_t idx = base + (size_t)(lane * 4 + i) * NOUT;
        float dv = e[i] * inv;
        lp[idx] = dv;
        pp[idx] = dv;
    }
}

extern "C" void kernel_launch(void* const* d_in, const int* in_sizes, int n_in,
                              void* d_out, int out_size, void* d_ws, size_t ws_size,
                              hipStream_t stream) {
    const float* hid  = (const float*)d_in[1];
    const float* emb  = (const float*)d_in[2];
    const float* wih0 = (const float*)d_in[3];
    const float* whh0 = (const float*)d_in[4];
    const float* bih0 = (const float*)d_in[5];
    const float* bhh0 = (const float*)d_in[6];
    const float* wih1 = (const float*)d_in[7];
    const float* whh1 = (const float*)d_in[8];
    const float* bih1 = (const float*)d_in[9];
    const float* bhh1 = (const float*)d_in[10];
    const float* fcw  = (const float*)d_in[11];
    const float* fcb  = (const float*)d_in[12];

    char*  ws = (char*)d_ws;
    half8* WP = (half8*)ws;                               // WP_BYTES + FP_BYTES
    float* T1 = (float*)(ws + WP_BYTES + FP_BYTES);       // 32*384 f32
    float* T0 = T1 + 32 * G3;                             // 384 f32

    prep_kernel<<<32, 384, 0, stream>>>(emb, wih0, bih0, T1, T0);
    prep_pack<<<75, 256, 0, stream>>>(whh0, wih1, whh1, fcw, WP);

    hipFuncSetAttribute((const void*)decoder_kernel,
                        hipFuncAttributeMaxDynamicSharedMemorySize, LDS_BYTES);
    decoder_kernel<<<NBLK, NTHR, LDS_BYTES, stream>>>(
        hid, T1, T0, ws, bhh0, bih1, bhh1, fcb, (float*)d_out);

    dur_kernel<<<BROWS / 4, 256, 0, stream>>>((float*)d_out);
}

// Round 14
// 2674.433 us; speedup vs baseline: 1.8528x; 1.1366x over previous
//
#include <hip/hip_runtime.h>

#define HDIM  128
#define G3    384
#define RPB   32
#define NTHR  512
#define NSTEP 256
#define NOUT  33
#define BROWS 8192
#define NBLK  (BROWS / RPB)      // 256 blocks -> 1 per CU
#define LOGP_ELEMS 69206016LL    // 8192*256*33

typedef _Float16 half8 __attribute__((ext_vector_type(8)));
typedef float    f32x4 __attribute__((ext_vector_type(4)));

// ---------------- LDS byte layout (155648 B, 1 block/CU) ----------------
#define HS0_OFF   0              // h0 splits: [32][256B] swz, split1 at +8192  (16384)
#define HS1_OFF   16384          //                                             (16384)
#define BST_OFF   32768          // ring: 8 waves x 12 slots x 1024 B          (98304)
#define FCL_OFF   131072         // fc weights 2-split: 3 nt x 4 kc x 2 s x 1024B (24576)
#define LDS_BYTES 155648

// ---------------- ws layout ----------------
#define WP_BYTES  294912         // 3 mats x 24 nt x 4 kc x 1024 B (single split)
#define FP_BYTES  24576          // fc: 3 nt x 4 kc x 2 s x 1024 B

__device__ __forceinline__ float sigf(float x) { return 1.0f / (1.0f + __expf(-x)); }
__device__ __forceinline__ float tanh_fast(float x) { return 1.0f - 2.0f / (__expf(2.0f*x) + 1.0f); }

// ---------------- prep: gi0 tables (fp32) ----------------
__global__ void prep_kernel(const float* __restrict__ emb, const float* __restrict__ wih0,
                            const float* __restrict__ bih0, float* __restrict__ T1,
                            float* __restrict__ T0) {
    int a = blockIdx.x;          // 0..31
    int g = threadIdx.x;         // 0..383
    const float* e = emb + a * 127;
    const float* w = wih0 + g * HDIM;
    float s = bih0[g];
    for (int k = 0; k < 127; ++k) s += e[k] * w[k];
    T1[a * G3 + g] = s + w[127];
    if (a == 0) T0[g] = s;
}

// ---------------- prep: pack weights (fp16 single split) + fc (2-split) ----------------
// lane holds B[g = nt*16 + (lane&15)][k = kc*32 + (lane>>4)*8 + e]
__global__ void prep_pack(const float* __restrict__ whh0, const float* __restrict__ wih1,
                          const float* __restrict__ whh1, const float* __restrict__ fcw,
                          half8* __restrict__ WP) {
    int b = blockIdx.x;            // 0..74 : 0-71 weight tiles, 72-74 fc
    int tid  = threadIdx.x;        // 256
    int lane = tid & 63;
    int kc   = tid >> 6;
    bool isfc = (b >= 72);
    if (!isfc) {
        int mat = b / 24, nt = b % 24;
        const float* W = (mat == 0) ? whh0 : (mat == 1) ? wih1 : whh1;
        int g = nt * 16 + (lane & 15);
        int k = kc * 32 + (lane >> 4) * 8;
        half8 v1;
#pragma unroll
        for (int e = 0; e < 8; ++e) v1[e] = (_Float16)W[g * HDIM + k + e];
        WP[(size_t)(((mat * 24 + nt) * 4 + kc)) * 64 + lane] = v1;
    } else {
        int nt = b - 72;
        int g = nt * 16 + (lane & 15);
        int k = kc * 32 + (lane >> 4) * 8;
        half8 v1, v2;
#pragma unroll
        for (int e = 0; e < 8; ++e) {
            float x = (g >= NOUT) ? 0.0f : fcw[g * HDIM + k + e];
            _Float16 s1 = (_Float16)x;
            v1[e] = s1; v2[e] = (_Float16)(x - (float)s1);
        }
        size_t base = (size_t)(WP_BYTES / 1024 + (nt * 4 + kc) * 2) * 64 + lane;
        WP[base]      = v1;
        WP[base + 64] = v2;
    }
}

// ---------------- main decoder: 3-barrier fused-phase structure ----------------
__launch_bounds__(NTHR, 2)
__global__ void decoder_kernel(const float* __restrict__ hid,
                               const float* __restrict__ T1, const float* __restrict__ T0,
                               const char* __restrict__ Bpg,
                               const float* __restrict__ bhh0,
                               const float* __restrict__ bih1, const float* __restrict__ bhh1,
                               const float* __restrict__ fcb,
                               float* __restrict__ out) {
    extern __shared__ char smraw[];
    char*  hs0 = smraw + HS0_OFF;
    char*  hs1 = smraw + HS1_OFF;
    char*  bst = smraw + BST_OFF;
    char*  fcl = smraw + FCL_OFF;

    const int tid  = threadIdx.x;
    const int row0 = blockIdx.x * RPB;
    float* lp = out;
    float* pp = out + LOGP_ELEMS;

    const int lane  = tid & 63;
    const int w     = tid >> 6;      // wave 0..7
    const int col   = lane & 15;
    const int q     = lane >> 4;
    const int akoff = q * 16;        // frag byte offset within 64B k-chunk
    const int j     = w * 16 + col;  // gate/hidden column owned by this lane
    char* const mybuf = bst + (size_t)w * 12288;   // 12 slots x 1024 B

    // hoisted per-lane biases
    const float bG0 = bhh0[j],       bG1 = bhh0[128 + j], bG2 = bhh0[256 + j];
    const float bH0 = bhh1[j],       bH1 = bhh1[128 + j], bH2 = bhh1[256 + j];
    const float bI0 = bih1[j],       bI1 = bih1[128 + j], bI2 = bih1[256 + j];

    // fc bias fragments: fcbr[t2][i] = fcb[16*t2 + q*4 + i] (0 beyond NOUT)
    f32x4 fcbr[3];
#pragma unroll
    for (int t2 = 0; t2 < 3; ++t2)
#pragma unroll
        for (int i = 0; i < 4; ++i) {
            int o = 16 * t2 + q * 4 + i;
            fcbr[t2][i] = (o < NOUT) ? fcb[o] : 0.0f;
        }

    // ---- stage fc weights to LDS (one-time) ----
    {
        const uint4* src = (const uint4*)(Bpg + WP_BYTES);
        uint4* dst = (uint4*)fcl;
        for (int i = tid; i < FP_BYTES / 16; i += NTHR) dst[i] = src[i];
    }

    // ---- init h0/h1 -> VGPRs + fp16 2-splits to LDS ----
    float h0v[2][4], h1v[2][4];
#pragma unroll
    for (int Mt = 0; Mt < 2; ++Mt)
#pragma unroll
        for (int i = 0; i < 4; ++i) {
            int row = Mt * 16 + q * 4 + i;
            float v0 = hid[(size_t)(row0 + row) * HDIM + j];
            float v1 = hid[(size_t)BROWS * HDIM + (size_t)(row0 + row) * HDIM + j];
            h0v[Mt][i] = v0; h1v[Mt][i] = v1;
            int off = (row * 256 + j * 2) ^ ((row & 7) << 4);
            _Float16 s1 = (_Float16)v0, s2 = (_Float16)(v0 - (float)s1);
            *(_Float16*)(hs0 + off) = s1;
            *(_Float16*)(hs0 + 8192 + off) = s2;
            s1 = (_Float16)v1; s2 = (_Float16)(v1 - (float)s1);
            *(_Float16*)(hs1 + off) = s1;
            *(_Float16*)(hs1 + 8192 + off) = s2;
        }
    __syncthreads();

#define LGKM0() asm volatile("s_waitcnt lgkmcnt(0)" ::: "memory")
#define VMW()   asm volatile("s_waitcnt vmcnt(9)" ::: "memory")
#define BAR()   __builtin_amdgcn_s_barrier()
#define MFMA(a, b, c) __builtin_amdgcn_mfma_f32_16x16x32_f16((a), (b), (c), 0, 0, 0)

    // Ring (verbatim R13): 12 groups/step of 3 chunks; group g: g<4 mat0, g<8 mat2,
    // else mat1; kc = g%4. Slot-base 3*(G%4) in a 12-slot ring; stage-ahead 3 groups;
    // vmcnt(9) exact by youngest-9; interloper VM ops only make waits stricter.
#define STAGE3(G_) do {                                                           \
        int gm_  = (G_) % 12;                                                     \
        int mat_ = (gm_ < 4) ? 0 : ((gm_ < 8) ? 2 : 1);                           \
        int kc_  = gm_ & 3;                                                       \
        char* db_ = mybuf + (size_t)(3 * ((G_) & 3)) * 1024;                      \
        _Pragma("unroll")                                                         \
        for (int ty_ = 0; ty_ < 3; ++ty_) {                                       \
            const char* src_ = Bpg + (size_t)(((mat_ * 24 + (ty_ * 8 + w)) * 4 + kc_) * 1024) + lane * 16; \
            __builtin_amdgcn_global_load_lds((const unsigned int*)src_,           \
                                             (unsigned int*)(db_ + ty_ * 1024), 16, 0, 0); \
        }                                                                         \
    } while (0)

#define GROUP(G_, HS_, ACC_) do {                                                 \
        STAGE3((G_) + 3);                                                         \
        VMW();                                                                    \
        int kc_ = (G_) & 3;                                                       \
        half8 a1_[2], a2_[2];                                                     \
        _Pragma("unroll")                                                         \
        for (int Mt_ = 0; Mt_ < 2; ++Mt_) {                                       \
            int row_ = Mt_ * 16 + col;                                            \
            int off_ = (row_ * 256 + kc_ * 64 + akoff) ^ ((row_ & 7) << 4);       \
            a1_[Mt_] = *(const half8*)((HS_) + off_);                             \
            a2_[Mt_] = *(const half8*)((HS_) + 8192 + off_);                      \
        }                                                                         \
        char* db_ = mybuf + (size_t)(3 * ((G_) & 3)) * 1024;                      \
        half8 b0_ = *(const half8*)(db_ + lane * 16);                             \
        half8 b1_ = *(const half8*)(db_ + 1024 + lane * 16);                      \
        half8 b2_ = *(const half8*)(db_ + 2048 + lane * 16);                      \
        _Pragma("unroll")                                                         \
        for (int Mt_ = 0; Mt_ < 2; ++Mt_) {                                       \
            ACC_[0][Mt_] = MFMA(a1_[Mt_], b0_, ACC_[0][Mt_]);                     \
            ACC_[0][Mt_] = MFMA(a2_[Mt_], b0_, ACC_[0][Mt_]);                     \
        }                                                                         \
        _Pragma("unroll")                                                         \
        for (int Mt_ = 0; Mt_ < 2; ++Mt_) {                                       \
            ACC_[1][Mt_] = MFMA(a1_[Mt_], b1_, ACC_[1][Mt_]);                     \
            ACC_[1][Mt_] = MFMA(a2_[Mt_], b1_, ACC_[1][Mt_]);                     \
        }                                                                         \
        _Pragma("unroll")                                                         \
        for (int Mt_ = 0; Mt_ < 2; ++Mt_) {                                       \
            ACC_[2][Mt_] = MFMA(a1_[Mt_], b2_, ACC_[2][Mt_]);                     \
            ACC_[2][Mt_] = MFMA(a2_[Mt_], b2_, ACC_[2][Mt_]);                     \
        }                                                                         \
    } while (0)

    // fc (operand-swapped: A=fcw, B=h1 -> bitwise-same sums, row-local layout)
    // + per-row softmax/argmax via 2-round shfl; stores on waves 0/1; acts in regs.
#define FC_SOFTMAX(TOUT_, ACTS_) do {                                             \
        f32x4 facc[2][3];                                                         \
        _Pragma("unroll")                                                         \
        for (int Mt_ = 0; Mt_ < 2; ++Mt_)                                         \
            _Pragma("unroll")                                                     \
            for (int t2_ = 0; t2_ < 3; ++t2_) facc[Mt_][t2_] = fcbr[t2_];         \
        _Pragma("unroll")                                                         \
        for (int kc_ = 0; kc_ < 4; ++kc_) {                                       \
            half8 a1_[2], a2_[2];                                                 \
            _Pragma("unroll")                                                     \
            for (int Mt_ = 0; Mt_ < 2; ++Mt_) {                                   \
                int row_ = Mt_ * 16 + col;                                        \
                int off_ = (row_ * 256 + kc_ * 64 + akoff) ^ ((row_ & 7) << 4);   \
                a1_[Mt_] = *(const half8*)(hs1 + off_);                           \
                a2_[Mt_] = *(const half8*)(hs1 + 8192 + off_);                    \
            }                                                                     \
            _Pragma("unroll")                                                     \
            for (int t2_ = 0; t2_ < 3; ++t2_) {                                   \
                half8 f1_ = *(const half8*)(fcl + ((t2_ * 4 + kc_) * 2 + 0) * 1024 + lane * 16); \
                half8 f2_ = *(const half8*)(fcl + ((t2_ * 4 + kc_) * 2 + 1) * 1024 + lane * 16); \
                _Pragma("unroll")                                                 \
                for (int Mt_ = 0; Mt_ < 2; ++Mt_) {                               \
                    facc[Mt_][t2_] = MFMA(f1_, a1_[Mt_], facc[Mt_][t2_]);         \
                    facc[Mt_][t2_] = MFMA(f1_, a2_[Mt_], facc[Mt_][t2_]);         \
                    facc[Mt_][t2_] = MFMA(f2_, a1_[Mt_], facc[Mt_][t2_]);         \
                }                                                                 \
            }                                                                     \
        }                                                                         \
        _Pragma("unroll")                                                         \
        for (int Mt_ = 0; Mt_ < 2; ++Mt_) {                                       \
            float bv_ = facc[Mt_][0][0]; int bi_ = q * 4;                         \
            _Pragma("unroll")                                                     \
            for (int t2_ = 0; t2_ < 2; ++t2_)                                     \
                _Pragma("unroll")                                                 \
                for (int i_ = 0; i_ < 4; ++i_) {                                  \
                    if (t2_ == 0 && i_ == 0) continue;                            \
                    float v_ = facc[Mt_][t2_][i_];                                \
                    int   o_ = 16 * t2_ + q * 4 + i_;                             \
                    if (v_ > bv_) { bv_ = v_; bi_ = o_; }                         \
                }                                                                 \
            _Pragma("unroll")                                                     \
            for (int d_ = 16; d_ <= 32; d_ <<= 1) {                               \
                float ov_ = __shfl_xor(bv_, d_);                                  \
                int   oi_ = __shfl_xor(bi_, d_);                                  \
                if (ov_ > bv_ || (ov_ == bv_ && oi_ < bi_)) { bv_ = ov_; bi_ = oi_; } \
            }                                                                     \
            (ACTS_)[Mt_] = bi_;                                                   \
            if (w == Mt_) {                                                       \
                float ex_[2][4]; float s_ = 0.0f;                                 \
                _Pragma("unroll")                                                 \
                for (int t2_ = 0; t2_ < 2; ++t2_)                                 \
                    _Pragma("unroll")                                             \
                    for (int i_ = 0; i_ < 4; ++i_) {                              \
                        ex_[t2_][i_] = __expf(facc[Mt_][t2_][i_] - bv_);          \
                        s_ += ex_[t2_][i_];                                       \
                    }                                                             \
                s_ += __shfl_xor(s_, 16);                                         \
                s_ += __shfl_xor(s_, 32);                                         \
                float ls_ = __logf(s_), inv_ = 1.0f / s_;                         \
                int r_ = lane & 15;                                               \
                size_t base_ = ((size_t)(row0 + Mt_ * 16 + r_) * NSTEP + (TOUT_)) * NOUT; \
                _Pragma("unroll")                                                 \
                for (int t2_ = 0; t2_ < 2; ++t2_)                                 \
                    _Pragma("unroll")                                             \
                    for (int i_ = 0; i_ < 4; ++i_) {                              \
                        int o_ = 16 * t2_ + q * 4 + i_;                           \
                        lp[base_ + o_] = facc[Mt_][t2_][i_] - bv_ - ls_;          \
                        pp[base_ + o_] = ex_[t2_][i_] * inv_;                     \
                    }                                                             \
                if (q == 0) lp[base_ + 32] = facc[Mt_][2][0];                     \
            }                                                                     \
        }                                                                         \
    } while (0)

    // prologue: stage groups 0..2 (9 chunks)
    STAGE3(0); STAGE3(1); STAGE3(2);

#pragma unroll 1
    for (int t = 0; t < NSTEP; ++t) {
        // ================= P1 =================
        float gi[3][2][4];
        if (t == 0) {
            float g0v = T0[j], g1v = T0[128 + j], g2v = T0[256 + j];
#pragma unroll
            for (int Mt = 0; Mt < 2; ++Mt)
#pragma unroll
                for (int i = 0; i < 4; ++i) {
                    gi[0][Mt][i] = g0v; gi[1][Mt][i] = g1v; gi[2][Mt][i] = g2v;
                }
        } else {
            int actsR[2];
            FC_SOFTMAX(t - 1, actsR);
            // acts -> per-thread gate rows via shfl (row Mt*16+q*4+i held by lane q*4+i)
#pragma unroll
            for (int Mt = 0; Mt < 2; ++Mt)
#pragma unroll
                for (int i = 0; i < 4; ++i) {
                    int act = __shfl(actsR[Mt], q * 4 + i);
                    const float* tab = T1 + act * G3;
                    gi[0][Mt][i] = tab[j];
                    gi[1][Mt][i] = tab[128 + j];
                    gi[2][Mt][i] = tab[256 + j];
                }
        }

        // phase A: gh0 (groups 0-3, hs0 old) and gh1 (groups 4-7, hs1 old)
        f32x4 g0[3][2], ah[3][2];
        {
            f32x4 v0 = {bG0, bG0, bG0, bG0}, v1 = {bG1, bG1, bG1, bG1}, v2 = {bG2, bG2, bG2, bG2};
            g0[0][0] = v0; g0[0][1] = v0; g0[1][0] = v1; g0[1][1] = v1; g0[2][0] = v2; g0[2][1] = v2;
            f32x4 u0 = {bH0, bH0, bH0, bH0}, u1 = {bH1, bH1, bH1, bH1}, u2 = {bH2, bH2, bH2, bH2};
            ah[0][0] = u0; ah[0][1] = u0; ah[1][0] = u1; ah[1][1] = u1; ah[2][0] = u2; ah[2][1] = u2;
        }
        GROUP(0, hs0, g0); GROUP(1, hs0, g0); GROUP(2, hs0, g0); GROUP(3, hs0, g0);
        GROUP(4, hs1, ah); GROUP(5, hs1, ah);

        // gates0 trans-compute to registers (g0 final after group 3) — co-issues with groups 6-7
        _Float16 s1r[2][4], s2r[2][4];
#pragma unroll
        for (int Mt = 0; Mt < 2; ++Mt)
#pragma unroll
            for (int i = 0; i < 4; ++i) {
                float rg = sigf(gi[0][Mt][i] + g0[0][Mt][i]);
                float zg = sigf(gi[1][Mt][i] + g0[1][Mt][i]);
                float ng = tanh_fast(gi[2][Mt][i] + rg * g0[2][Mt][i]);
                float hnew = (1.0f - zg) * ng + zg * h0v[Mt][i];
                h0v[Mt][i] = hnew;
                s1r[Mt][i] = (_Float16)hnew;
                s2r[Mt][i] = (_Float16)(hnew - (float)s1r[Mt][i]);
            }

        GROUP(6, hs1, ah); GROUP(7, hs1, ah);
        LGKM0(); BAR();   // BAR1: all hs0/hs1 reads of this step done

        // ================= P2: hs0 split writes =================
#pragma unroll
        for (int Mt = 0; Mt < 2; ++Mt)
#pragma unroll
            for (int i = 0; i < 4; ++i) {
                int row = Mt * 16 + q * 4 + i;
                int off = (row * 256 + j * 2) ^ ((row & 7) << 4);
                *(_Float16*)(hs0 + off) = s1r[Mt][i];
                *(_Float16*)(hs0 + 8192 + off) = s2r[Mt][i];
            }
        LGKM0(); BAR();   // BAR2: hs0_new visible

        // ================= P3: gi1 (groups 8-11, hs0_new) + gates1 =================
        f32x4 ai[3][2];
        {
            f32x4 v0 = {bI0, bI0, bI0, bI0}, v1 = {bI1, bI1, bI1, bI1}, v2 = {bI2, bI2, bI2, bI2};
            ai[0][0] = v0; ai[0][1] = v0; ai[1][0] = v1; ai[1][1] = v1; ai[2][0] = v2; ai[2][1] = v2;
        }
        GROUP(8, hs0, ai); GROUP(9, hs0, ai); GROUP(10, hs0, ai); GROUP(11, hs0, ai);

#pragma unroll
        for (int Mt = 0; Mt < 2; ++Mt)
#pragma unroll
            for (int i = 0; i < 4; ++i) {
                float rg = sigf(ai[0][Mt][i] + ah[0][Mt][i]);
                float zg = sigf(ai[1][Mt][i] + ah[1][Mt][i]);
                float ng = tanh_fast(ai[2][Mt][i] + rg * ah[2][Mt][i]);
                float hnew = (1.0f - zg) * ng + zg * h1v[Mt][i];
                h1v[Mt][i] = hnew;
                int row = Mt * 16 + q * 4 + i;
                int off = (row * 256 + j * 2) ^ ((row & 7) << 4);
                _Float16 s1 = (_Float16)hnew, s2 = (_Float16)(hnew - (float)s1);
                *(_Float16*)(hs1 + off) = s1;
                *(_Float16*)(hs1 + 8192 + off) = s2;
            }
        LGKM0(); BAR();   // BAR3: hs1_new visible for next P1
    }

    // epilogue: outputs for step 255
    {
        int actsF[2];
        FC_SOFTMAX(NSTEP - 1, actsF);
        (void)actsF;
    }
#undef STAGE3
#undef GROUP
#undef FC_SOFTMAX
#undef LGKM0
#undef VMW
#undef BAR
#undef MFMA
}

// ---------------- duration softmax over time ----------------
__global__ void dur_kernel(float* __restrict__ out) {
    int wid  = threadIdx.x >> 6;
    int lane = threadIdx.x & 63;
    int row  = blockIdx.x * 4 + wid;
    float* lp = out;
    float* pp = out + LOGP_ELEMS;
    size_t base = (size_t)row * NSTEP * NOUT + 32;

    float v[4]; float m = -1e30f;
#pragma unroll
    for (int i = 0; i < 4; ++i) {
        v[i] = lp[base + (size_t)(lane * 4 + i) * NOUT];
        m = fmaxf(m, v[i]);
    }
#pragma unroll
    for (int d = 1; d < 64; d <<= 1) m = fmaxf(m, __shfl_xor(m, d));
    float e[4]; float s = 0.0f;
#pragma unroll
    for (int i = 0; i < 4; ++i) { e[i] = __expf(v[i] - m); s += e[i]; }
#pragma unroll
    for (int d = 1; d < 64; d <<= 1) s += __shfl_xor(s, d);
    float inv = 1.0f / s;
#pragma unroll
    for (int i = 0; i < 4; ++i) {
        size_t idx = base + (size_t)(lane * 4 + i) * NOUT;
        float dv = e[i] * inv;
        lp[idx] = dv;
        pp[idx] = dv;
    }
}

extern "C" void kernel_launch(void* const* d_in, const int* in_sizes, int n_in,
                              void* d_out, int out_size, void* d_ws, size_t ws_size,
                              hipStream_t stream) {
    const float* hid  = (const float*)d_in[1];
    const float* emb  = (const float*)d_in[2];
    const float* wih0 = (const float*)d_in[3];
    const float* whh0 = (const float*)d_in[4];
    const float* bih0 = (const float*)d_in[5];
    const float* bhh0 = (const float*)d_in[6];
    const float* wih1 = (const float*)d_in[7];
    const float* whh1 = (const float*)d_in[8];
    const float* bih1 = (const float*)d_in[9];
    const float* bhh1 = (const float*)d_in[10];
    const float* fcw  = (const float*)d_in[11];
    const float* fcb  = (const float*)d_in[12];

    char*  ws = (char*)d_ws;
    half8* WP = (half8*)ws;                               // WP_BYTES + FP_BYTES
    float* T1 = (float*)(ws + WP_BYTES + FP_BYTES);       // 32*384 f32
    float* T0 = T1 + 32 * G3;                             // 384 f32

    prep_kernel<<<32, 384, 0, stream>>>(emb, wih0, bih0, T1, T0);
    prep_pack<<<75, 256, 0, stream>>>(whh0, wih1, whh1, fcw, WP);

    hipFuncSetAttribute((const void*)decoder_kernel,
                        hipFuncAttributeMaxDynamicSharedMemorySize, LDS_BYTES);
    decoder_kernel<<<NBLK, NTHR, LDS_BYTES, stream>>>(
        hid, T1, T0, ws, bhh0, bih1, bhh1, fcb, (float*)d_out);

    dur_kernel<<<BROWS / 4, 256, 0, stream>>>((float*)d_out);
}